// Round 5
// baseline (400.952 us; speedup 1.0000x reference)
//
#include <hip/hip_runtime.h>

// TCM_77464030151162: x(N,128)@w1+b1 -> split 64/64 -> two gathered 3^3 sparse
// convs (27 offsets, 64x64 each, ReLU) -> +2*conv_x residual -> concat@w2+b2 -> +x.
// fp32 wire, bf16 MFMA compute.
// R9: conv = R6's barrier-free register-B structure with the TLP arithmetic
// fixed: 32 rows/wave (not 64) -> 3125 waves = 3.05/SIMD (R6 was 1.5/SIMD and
// that alone explained its 80 us). 100000 = 3125*32: zero tail, no row checks.
// No LDS, no barriers, no asm waits; B double-buffered in regs (weights L1/L2
// resident); A-gather dist 1; idx ring dist 3; all ring indices compile-time.
// ~155 VGPR, __launch_bounds__(64,3) -> 12 waves/CU. Evidence: R4/R5/R8 show
// any per-k barrier costs ~47-64 us regardless of vmcnt strategy; R6 shows
// barrier-free scales with waves/SIMD. k_prep: rwT back to plain transpose
// (no LDS -> no swizzle). GEMMs unchanged (their counters surface next).

#define N_PTS 100000
#define NBLK64 1563   // ceil(100000/64)
#define NBLK32 3125   // 100000/32 exact
#define NBLK128 782   // ceil(100000/128)

typedef __attribute__((ext_vector_type(8))) short frag_ab; // 8 bf16 (4 VGPRs)
typedef __attribute__((ext_vector_type(4))) float f32x4;   // MFMA 16x16 C/D
#define ZFRAG frag_ab{0, 0, 0, 0, 0, 0, 0, 0}

__device__ __forceinline__ unsigned short f2bf(float f) {
  union { float f; unsigned int i; } v; v.f = f;
  unsigned int r = v.i + 0x7fffu + ((v.i >> 16) & 1u); // RNE
  return (unsigned short)(r >> 16);
}
__device__ __forceinline__ float bf2f(unsigned short u) {
  union { unsigned int i; float f; } v; v.i = ((unsigned int)u) << 16; return v.f;
}

// async global->LDS, 16B per lane. LDS dest = wave-uniform base + lane*16 (m104).
__device__ __forceinline__ void gload_lds16(const unsigned short* g, unsigned short* l) {
  __builtin_amdgcn_global_load_lds(
      (const __attribute__((address_space(1))) unsigned int*)g,
      (__attribute__((address_space(3))) unsigned int*)(unsigned int)(size_t)l,
      16, 0, 0);
}

// ---- weight convert+transpose ----
// w1T/w2T (LDS-staged GEMMs): logical (d,c); 16B chunk (c>>3) stored at
// chunk^(d&15) (XOR swizzle baked in for bank-conflict-free ds_read).
// rw1T/rw2T (read direct global->reg by conv): plain transposed d-major,
// rwT[k][d][c] = bf16(rw[k][c][d]) -- no swizzle (no LDS involved).
__global__ __launch_bounds__(256) void k_prep(
    const float* __restrict__ w1, const float* __restrict__ w2,
    const float* __restrict__ rw1, const float* __restrict__ rw2,
    unsigned short* __restrict__ w1T, unsigned short* __restrict__ w2T,
    unsigned short* __restrict__ rw1T, unsigned short* __restrict__ rw2T) {
  int t = blockIdx.x * 256 + threadIdx.x;
  if (t < 128 * 128) {
    int c = t >> 7, d = t & 127;
    int pos = d * 128 + ((((c >> 3) ^ (d & 15)) << 3) | (c & 7));
    w1T[pos] = f2bf(w1[t]);
    w2T[pos] = f2bf(w2[t]);
  }
  if (t < 27 * 64 * 64) {
    int k = t >> 12, r = t & 4095, c = r >> 6, d = r & 63;
    int pos = (k << 12) + d * 64 + c;
    rw1T[pos] = f2bf(rw1[t]);
    rw2T[pos] = f2bf(rw2[t]);
  }
}

// ---- y = bf16(x) @ w1 + b1 ; w1T staged in LDS once; 16 rows/wave ----
__global__ __launch_bounds__(256) void k_gemm_in(
    const float* __restrict__ x, const unsigned short* __restrict__ w1T,
    const float* __restrict__ b1, unsigned short* __restrict__ y) {
  __shared__ unsigned short sw[16384]; // 32KB
  const int tid = threadIdx.x, lane = tid & 63, w = tid >> 6;
  const int m16 = lane & 15, q = lane >> 4;
#pragma unroll
  for (int r = 0; r < 8; ++r) {
    const int off = (w * 8 + r) * 512 + lane * 8;
    gload_lds16(w1T + off, &sw[off]);
  }
  __syncthreads();
  const int rowbase = blockIdx.x * 64 + w * 16;
  const int r0 = rowbase + m16;
  const int rc = r0 < N_PTS ? r0 : N_PTS - 1;
  f32x4 acc[8] = {};
#pragma unroll
  for (int kk = 0; kk < 4; ++kk) {
    const float* xp = x + (size_t)rc * 128 + kk * 32 + q * 8;
    float4 f0 = *(const float4*)xp;
    float4 f1 = *(const float4*)(xp + 4);
    frag_ab a;
    a[0] = (short)f2bf(f0.x); a[1] = (short)f2bf(f0.y);
    a[2] = (short)f2bf(f0.z); a[3] = (short)f2bf(f0.w);
    a[4] = (short)f2bf(f1.x); a[5] = (short)f2bf(f1.y);
    a[6] = (short)f2bf(f1.z); a[7] = (short)f2bf(f1.w);
#pragma unroll
    for (int ct = 0; ct < 8; ++ct) {
      const int d = ct * 16 + m16;
      const int phys = ((kk << 2) | q) ^ m16;
      frag_ab bf = *(const frag_ab*)(&sw[d * 128 + phys * 8]);
      acc[ct] = __builtin_amdgcn_mfma_f32_16x16x32_bf16(a, bf, acc[ct], 0, 0, 0);
    }
  }
#pragma unroll
  for (int ct = 0; ct < 8; ++ct) {
    const int col = ct * 16 + m16;
    const float bias = b1[col];
#pragma unroll
    for (int j = 0; j < 4; ++j) {
      int r = rowbase + q * 4 + j;
      if (r < N_PTS) y[(size_t)r * 128 + col] = f2bf(acc[ct][j] + bias);
    }
  }
}

// ---- gathered sparse conv: barrier-free, 1 wave/block, 32 rows/wave ----
// No LDS, no syncthreads. B-fragments direct global->reg (weights L2/L1
// resident, identical layout+addressing to R6 which passed refcheck).
// Rings: I dist-3 (mod 4), A dist-1 (parity), B dist-1 (parity).
template <bool FUSE>
__global__ __launch_bounds__(64, 3) void k_conv(
    const unsigned short* __restrict__ feat, const int fstride,
    const int* __restrict__ nbr,
    const unsigned short* __restrict__ rwT, const float* __restrict__ rb,
    const unsigned short* __restrict__ res, unsigned short* __restrict__ out) {
  const int lane = threadIdx.x & 63;
  const int m16 = lane & 15, q = lane >> 4;
  const int rowbase = blockIdx.x * 32; // exact: 3125*32 = 100000, no tail
  const int p0 = rowbase + m16, p1 = p0 + 16;

  int I[4][2];        // raw nbr ring
  int im[2][2];       // masked idx for A slot (zero-select at consume)
  frag_ab A[2][2][2]; // [slot][rt][kk]
  frag_ab B[2][4][2]; // [slot][ct][kk]
  f32x4 acc[2][4] = {};

#define CONV_LOADI(s, kidx)                                                     \
  {                                                                             \
    I[s][0] = nbr[(size_t)(kidx) * N_PTS + p0];                                 \
    I[s][1] = nbr[(size_t)(kidx) * N_PTS + p1];                                 \
  }

#define CONV_LOADB(slot, kidx)                                                  \
  _Pragma("unroll") for (int ct = 0; ct < 4; ++ct)                              \
    _Pragma("unroll") for (int kk = 0; kk < 2; ++kk)                            \
      B[slot][ct][kk] = *(const frag_ab*)(rwT + ((size_t)(kidx) << 12) +        \
                                          (ct * 16 + m16) * 64 + kk * 32 + q * 8);

#define CONV_GATHER(slot, isrc)                                                 \
  {                                                                             \
    const int i0 = (isrc)[0];                                                   \
    const int i1 = (isrc)[1];                                                   \
    im[slot][0] = i0; im[slot][1] = i1;                                         \
    const size_t j0 = (size_t)(i0 < 0 ? 0 : i0);                                \
    const size_t j1 = (size_t)(i1 < 0 ? 0 : i1);                                \
    const unsigned short* f0 = feat + j0 * fstride + q * 8;                     \
    const unsigned short* f1 = feat + j1 * fstride + q * 8;                     \
    A[slot][0][0] = *(const frag_ab*)f0; A[slot][0][1] = *(const frag_ab*)(f0 + 32); \
    A[slot][1][0] = *(const frag_ab*)f1; A[slot][1][1] = *(const frag_ab*)(f1 + 32); \
  }

#define CONV_COMPUTE(slot)                                                      \
  {                                                                             \
    frag_ab Ac[2][2];                                                           \
    _Pragma("unroll") for (int rt = 0; rt < 2; ++rt)                            \
      _Pragma("unroll") for (int kk = 0; kk < 2; ++kk) {                        \
        frag_ab a = A[slot][rt][kk];                                            \
        if (im[slot][rt] < 0) a = ZFRAG;                                        \
        Ac[rt][kk] = a;                                                         \
      }                                                                         \
    _Pragma("unroll") for (int kk = 0; kk < 2; ++kk)                            \
      _Pragma("unroll") for (int ct = 0; ct < 4; ++ct) {                        \
        acc[0][ct] = __builtin_amdgcn_mfma_f32_16x16x32_bf16(Ac[0][kk], B[slot][ct][kk], acc[0][ct], 0, 0, 0); \
        acc[1][ct] = __builtin_amdgcn_mfma_f32_16x16x32_bf16(Ac[1][kk], B[slot][ct][kk], acc[1][ct], 0, 0, 0); \
      }                                                                         \
  }

  // ---- prologue: I for k=0,1,2; B and A for k=0 ----
  CONV_LOADI(0, 0);
  CONV_LOADI(1, 1);
  CONV_LOADI(2, 2);
  CONV_LOADB(0, 0);
  CONV_GATHER(0, I[0]);

  // ---- main loop k = 0..23 (outer runtime, inner unrolled; ring idx static) ----
  for (int k0 = 0; k0 < 24; k0 += 4) {
#pragma unroll
    for (int u = 0; u < 4; ++u) {
      const int k = k0 + u;
      CONV_LOADI((u + 3) & 3, k + 3);        // k+3 <= 26
      CONV_LOADB((u + 1) & 1, k + 1);        // k+1 <= 24
      CONV_GATHER((u + 1) & 1, I[(u + 1) & 3]);
      CONV_COMPUTE(u & 1);
    }
  }

  // ---- epilogue k = 24 (slot 0), 25 (slot 1), 26 (slot 0) ----
  CONV_LOADB(1, 25);
  CONV_GATHER(1, I[1]); // k=25: 25&3 == 1
  CONV_COMPUTE(0);      // k=24
  CONV_LOADB(0, 26);
  CONV_GATHER(0, I[2]); // k=26: 26&3 == 2
  CONV_COMPUTE(1);      // k=25
  CONV_COMPUTE(0);      // k=26

#undef CONV_LOADI
#undef CONV_LOADB
#undef CONV_GATHER
#undef CONV_COMPUTE

#pragma unroll
  for (int ct = 0; ct < 4; ++ct) {
    const int col = ct * 16 + m16;
    const float bias = rb[col];
#pragma unroll
    for (int rt = 0; rt < 2; ++rt)
#pragma unroll
      for (int j = 0; j < 4; ++j) {
        const int r = rowbase + rt * 16 + q * 4 + j; // always < N_PTS (no tail)
        float v = acc[rt][ct][j] + bias;
        v = v > 0.f ? v : 0.f;
        if constexpr (FUSE) v += 2.f * bf2f(res[(size_t)r * 128 + col]);
        out[(size_t)r * 64 + col] = f2bf(v);
      }
  }
}

// ---- out = x + [z1 | y[:,64:]] @ w2 + b2 ; w2T staged in LDS once; 16 rows/wave ----
__global__ __launch_bounds__(256) void k_gemm_out(
    const float* __restrict__ x, const unsigned short* __restrict__ z1,
    const unsigned short* __restrict__ y, const unsigned short* __restrict__ w2T,
    const float* __restrict__ b2, float* __restrict__ out) {
  __shared__ unsigned short sw[16384]; // 32KB
  const int tid = threadIdx.x, lane = tid & 63, w = tid >> 6;
  const int m16 = lane & 15, q = lane >> 4;
#pragma unroll
  for (int r = 0; r < 8; ++r) {
    const int off = (w * 8 + r) * 512 + lane * 8;
    gload_lds16(w2T + off, &sw[off]);
  }
  __syncthreads();
  const int rowbase = blockIdx.x * 64 + w * 16;
  const int r0 = rowbase + m16;
  const int rc = r0 < N_PTS ? r0 : N_PTS - 1;
  f32x4 acc[8] = {};
#pragma unroll
  for (int kk = 0; kk < 4; ++kk) {
    const unsigned short* ap = (kk < 2)
        ? (z1 + (size_t)rc * 64 + kk * 32 + q * 8)
        : (y + (size_t)rc * 128 + 64 + (kk - 2) * 32 + q * 8);
    frag_ab a = *(const frag_ab*)ap;
#pragma unroll
    for (int ct = 0; ct < 8; ++ct) {
      const int d = ct * 16 + m16;
      const int phys = ((kk << 2) | q) ^ m16;
      frag_ab bf = *(const frag_ab*)(&sw[d * 128 + phys * 8]);
      acc[ct] = __builtin_amdgcn_mfma_f32_16x16x32_bf16(a, bf, acc[ct], 0, 0, 0);
    }
  }
#pragma unroll
  for (int ct = 0; ct < 8; ++ct) {
    const int col = ct * 16 + m16;
    const float bias = b2[col];
#pragma unroll
    for (int j = 0; j < 4; ++j) {
      int r = rowbase + q * 4 + j;
      if (r < N_PTS) {
        size_t o = (size_t)r * 128 + col;
        out[o] = acc[ct][j] + bias + x[o];
      }
    }
  }
}

extern "C" void kernel_launch(void* const* d_in, const int* in_sizes, int n_in,
                              void* d_out, int out_size, void* d_ws, size_t ws_size,
                              hipStream_t stream) {
  const float* x   = (const float*)d_in[0];
  const float* w1  = (const float*)d_in[1];
  const float* b1  = (const float*)d_in[2];
  const float* w2  = (const float*)d_in[3];
  const float* b2  = (const float*)d_in[4];
  const float* rw1 = (const float*)d_in[5];
  const float* rb1 = (const float*)d_in[6];
  const float* rw2 = (const float*)d_in[7];
  const float* rb2 = (const float*)d_in[8];
  const int* nbr = (const int*)d_in[9];
  float* out = (float*)d_out;

  char* ws = (char*)d_ws;
  unsigned short* w1T  = (unsigned short*)(ws);                       // 32 KB
  unsigned short* w2T  = (unsigned short*)(ws + 32768);               // 32 KB
  unsigned short* rw1T = (unsigned short*)(ws + 65536);               // 216 KB
  unsigned short* rw2T = (unsigned short*)(ws + 286720);              // 216 KB
  unsigned short* y    = (unsigned short*)(ws + 507904);              // 25.6 MB
  unsigned short* r1   = (unsigned short*)(ws + 507904 + 25600000);   // 12.8 MB
  unsigned short* z1   = (unsigned short*)(ws + 507904 + 38400000);   // 12.8 MB

  k_prep<<<432, 256, 0, stream>>>(w1, w2, rw1, rw2, w1T, w2T, rw1T, rw2T);
  k_gemm_in<<<NBLK64, 256, 0, stream>>>(x, w1T, b1, y);
  k_conv<false><<<NBLK32, 64, 0, stream>>>(y, 128, nbr, rw1T, rb1, nullptr, r1);
  k_conv<true><<<NBLK32, 64, 0, stream>>>(r1, 64, nbr, rw2T, rb2, y, z1);
  k_gemm_out<<<NBLK64, 256, 0, stream>>>(x, z1, y, w2T, b2, out);
}

// Round 6
// 290.425 us; speedup vs baseline: 1.3806x; 1.3806x over previous
//
#include <hip/hip_runtime.h>

// TCM_77464030151162: x(N,128)@w1+b1 -> split 64/64 -> two gathered 3^3 sparse
// convs (27 offsets, 64x64 each, ReLU) -> +2*conv_x residual -> concat@w2+b2 -> +x.
// fp32 wire, bf16 MFMA compute.
// R10: deep-pipelined conv. Model from R4/R6/R8/R9: all previous structures had
// <=1 iter of gather-prefetch cover vs ~600-900cy L3 random-gather latency ->
// per-k one exposed round-trip regardless of barrier protocol. Now: R4 geometry
// (128 rows/block, 4 waves, grid 782, LDS-shared B) + R8's verified counted-vmcnt
// protocol at depth 2: nbr in LDS slab (prologue, 13.5KB), per-iter vmem = 6 fixed
// ops (stage k+3 x2, gather k+2 x4), vmcnt(12) = 2 iters in flight, B-ring 4x8KB,
// raw s_barrier. NO sched_barrier(0) (R8/m141 lesson). Stage-visibility: issued
// at k, own-vmcnt-retired at k+2, barrier, read at k+3. Write slot (k+3)&3 =
// slot read at k-1, one-barrier separation (R8's passing discipline).

#define N_PTS 100000
#define NBLK64 1563  // ceil(100000/64)
#define NBLK128 782  // ceil(100000/128)

typedef __attribute__((ext_vector_type(8))) short frag_ab; // 8 bf16 (4 VGPRs)
typedef __attribute__((ext_vector_type(4))) float f32x4;   // MFMA 16x16 C/D
#define ZFRAG frag_ab{0, 0, 0, 0, 0, 0, 0, 0}

__device__ __forceinline__ unsigned short f2bf(float f) {
  union { float f; unsigned int i; } v; v.f = f;
  unsigned int r = v.i + 0x7fffu + ((v.i >> 16) & 1u); // RNE
  return (unsigned short)(r >> 16);
}
__device__ __forceinline__ float bf2f(unsigned short u) {
  union { unsigned int i; float f; } v; v.i = ((unsigned int)u) << 16; return v.f;
}

// async global->LDS, 16B per lane. LDS dest = wave-uniform base + lane*16 (m104).
__device__ __forceinline__ void gload_lds16(const unsigned short* g, unsigned short* l) {
  __builtin_amdgcn_global_load_lds(
      (const __attribute__((address_space(1))) unsigned int*)g,
      (__attribute__((address_space(3))) unsigned int*)(unsigned int)(size_t)l,
      16, 0, 0);
}

// ---- weight convert+transpose+swizzle ----
// w1T/w2T: logical (d,c); 16B chunk (c>>3) stored at chunk^(d&15).
// rw1T/rw2T: (k,d,c) 64x64; chunk (c>>3) stored at chunk^(d&7) (swizzle baked
// into global layout so linear gload_lds staging lands swizzled in LDS).
__global__ __launch_bounds__(256) void k_prep(
    const float* __restrict__ w1, const float* __restrict__ w2,
    const float* __restrict__ rw1, const float* __restrict__ rw2,
    unsigned short* __restrict__ w1T, unsigned short* __restrict__ w2T,
    unsigned short* __restrict__ rw1T, unsigned short* __restrict__ rw2T) {
  int t = blockIdx.x * 256 + threadIdx.x;
  if (t < 128 * 128) {
    int c = t >> 7, d = t & 127;
    int pos = d * 128 + ((((c >> 3) ^ (d & 15)) << 3) | (c & 7));
    w1T[pos] = f2bf(w1[t]);
    w2T[pos] = f2bf(w2[t]);
  }
  if (t < 27 * 64 * 64) {
    int k = t >> 12, r = t & 4095, c = r >> 6, d = r & 63;
    int pos = (k << 12) + d * 64 + ((((c >> 3) ^ (d & 7)) << 3) | (c & 7));
    rw1T[pos] = f2bf(rw1[t]);
    rw2T[pos] = f2bf(rw2[t]);
  }
}

// ---- y = bf16(x) @ w1 + b1 ; w1T staged in LDS once; 16 rows/wave ----
__global__ __launch_bounds__(256) void k_gemm_in(
    const float* __restrict__ x, const unsigned short* __restrict__ w1T,
    const float* __restrict__ b1, unsigned short* __restrict__ y) {
  __shared__ unsigned short sw[16384]; // 32KB
  const int tid = threadIdx.x, lane = tid & 63, w = tid >> 6;
  const int m16 = lane & 15, q = lane >> 4;
#pragma unroll
  for (int r = 0; r < 8; ++r) {
    const int off = (w * 8 + r) * 512 + lane * 8;
    gload_lds16(w1T + off, &sw[off]);
  }
  __syncthreads();
  const int rowbase = blockIdx.x * 64 + w * 16;
  const int r0 = rowbase + m16;
  const int rc = r0 < N_PTS ? r0 : N_PTS - 1;
  f32x4 acc[8] = {};
#pragma unroll
  for (int kk = 0; kk < 4; ++kk) {
    const float* xp = x + (size_t)rc * 128 + kk * 32 + q * 8;
    float4 f0 = *(const float4*)xp;
    float4 f1 = *(const float4*)(xp + 4);
    frag_ab a;
    a[0] = (short)f2bf(f0.x); a[1] = (short)f2bf(f0.y);
    a[2] = (short)f2bf(f0.z); a[3] = (short)f2bf(f0.w);
    a[4] = (short)f2bf(f1.x); a[5] = (short)f2bf(f1.y);
    a[6] = (short)f2bf(f1.z); a[7] = (short)f2bf(f1.w);
#pragma unroll
    for (int ct = 0; ct < 8; ++ct) {
      const int d = ct * 16 + m16;
      const int phys = ((kk << 2) | q) ^ m16;
      frag_ab bf = *(const frag_ab*)(&sw[d * 128 + phys * 8]);
      acc[ct] = __builtin_amdgcn_mfma_f32_16x16x32_bf16(a, bf, acc[ct], 0, 0, 0);
    }
  }
#pragma unroll
  for (int ct = 0; ct < 8; ++ct) {
    const int col = ct * 16 + m16;
    const float bias = b1[col];
#pragma unroll
    for (int j = 0; j < 4; ++j) {
      int r = rowbase + q * 4 + j;
      if (r < N_PTS) y[(size_t)r * 128 + col] = f2bf(acc[ct][j] + bias);
    }
  }
}

// ---- gathered sparse conv: depth-2 counted-vmcnt pipeline ----
// 128 rows/block (4 waves x 32 rows). nbr pre-staged in LDS slab. Per main-loop
// iter k (0..23): [I-prefetch k+3 from slab (LDS)], stage weights k+3 (2
// global_load_lds -> slot (k+3)&3), gather A for k+2 (4 loads via Ireg), then
// s_waitcnt vmcnt(12) (leaves iters k-? none: exactly iters k-0... leaves the
// newest 12 = iters k,k-1 in flight; everything >=2 iters old retired),
// ds_read B slot k&3 + 16 MFMA, raw s_barrier. Epilogue k=24/25/26 with exact
// waits vmcnt(10)/(4)/(0). All per-iter vmem counts fixed, addresses unique.
template <bool FUSE>
__global__ __launch_bounds__(256) void k_conv(
    const unsigned short* __restrict__ feat, const int fstride,
    const int* __restrict__ nbr,
    const unsigned short* __restrict__ rwT, const float* __restrict__ rb,
    const unsigned short* __restrict__ res, unsigned short* __restrict__ out) {
  __shared__ unsigned short sw[4][4096]; // B-ring: 4 x 8KB
  __shared__ int isl[27 * 128];          // nbr slab: 13.5KB
  const int tid = threadIdx.x, lane = tid & 63, w = tid >> 6;
  const int m16 = lane & 15, q = lane >> 4;
  const int rowbase = blockIdx.x * 128 + w * 32;
  const int s0 = w * 1024 + lane * 8; // ushort idx of this thread's 16B chunk
  const int s1 = s0 + 512;
  const int ibase = w * 32 + m16;     // this thread's row pair in the slab

  // ---- prologue A: nbr -> LDS slab (guarded tail writes -1) ----
  for (int i = tid; i < 27 * 128; i += 256) {
    const int kk = i >> 7, r = i & 127;
    const int row = blockIdx.x * 128 + r;
    isl[i] = (row < N_PTS) ? nbr[(size_t)kk * N_PTS + row] : -1;
  }
  __syncthreads(); // full drain OK here; resets vmcnt baseline to 0

  int Ireg[2][2];     // I prefetch ring (dist 1 from slab)
  int im[4][2];       // mask ring, slot (k+2)&3
  frag_ab A[4][2][2]; // A ring, slot (k+2)&3
  f32x4 acc[2][4] = {};

#define CONV_GATHER(aslot, i0v, i1v)                                            \
  {                                                                             \
    const int gi0 = (i0v), gi1 = (i1v);                                         \
    im[aslot][0] = gi0; im[aslot][1] = gi1;                                     \
    const size_t j0 = (size_t)(gi0 < 0 ? 0 : gi0);                              \
    const size_t j1 = (size_t)(gi1 < 0 ? 0 : gi1);                              \
    const unsigned short* f0 = feat + j0 * fstride + q * 8;                     \
    const unsigned short* f1 = feat + j1 * fstride + q * 8;                     \
    A[aslot][0][0] = *(const frag_ab*)f0; A[aslot][0][1] = *(const frag_ab*)(f0 + 32); \
    A[aslot][1][0] = *(const frag_ab*)f1; A[aslot][1][1] = *(const frag_ab*)(f1 + 32); \
  }

#define CONV_COMPUTE(bslot, aslot)                                              \
  {                                                                             \
    frag_ab Ac[2][2];                                                           \
    _Pragma("unroll") for (int rt = 0; rt < 2; ++rt)                            \
      _Pragma("unroll") for (int kk = 0; kk < 2; ++kk) {                        \
        frag_ab a = A[aslot][rt][kk];                                           \
        if (im[aslot][rt] < 0) a = ZFRAG;                                       \
        Ac[rt][kk] = a;                                                         \
      }                                                                         \
    _Pragma("unroll") for (int kk = 0; kk < 2; ++kk)                            \
      _Pragma("unroll") for (int ct = 0; ct < 4; ++ct) {                        \
        const int d = ct * 16 + m16;                                            \
        const int phys = ((kk << 2) | q) ^ (m16 & 7);                           \
        frag_ab bf = *(const frag_ab*)(&sw[bslot][d * 64 + phys * 8]);          \
        acc[0][ct] = __builtin_amdgcn_mfma_f32_16x16x32_bf16(Ac[0][kk], bf, acc[0][ct], 0, 0, 0); \
        acc[1][ct] = __builtin_amdgcn_mfma_f32_16x16x32_bf16(Ac[1][kk], bf, acc[1][ct], 0, 0, 0); \
      }                                                                         \
  }

  // ---- prologue B: stage 0..2, gathers 0,1, I-prefetch offset 2 ----
  gload_lds16(rwT + s0, &sw[0][s0]);
  gload_lds16(rwT + s1, &sw[0][s1]);
  gload_lds16(rwT + 4096 + s0, &sw[1][s0]);
  gload_lds16(rwT + 4096 + s1, &sw[1][s1]);
  gload_lds16(rwT + 8192 + s0, &sw[2][s0]);
  gload_lds16(rwT + 8192 + s1, &sw[2][s1]);
  Ireg[0][0] = isl[2 * 128 + ibase];        // offset 2 -> slot 2&1 = 0
  Ireg[0][1] = isl[2 * 128 + ibase + 16];
  CONV_GATHER(0, isl[0 * 128 + ibase], isl[0 * 128 + ibase + 16]); // offset 0
  CONV_GATHER(1, isl[1 * 128 + ibase], isl[1 * 128 + ibase + 16]); // offset 1
  asm volatile("s_waitcnt vmcnt(8)" ::: "memory"); // retire 6 stages, 8 gathers in flight
  __builtin_amdgcn_s_barrier();

  // ---- main loop k = 0..23 (outer runtime k0%4==0, inner unrolled: static idx) ----
  for (int k0 = 0; k0 < 24; k0 += 4) {
#pragma unroll
    for (int u = 0; u < 4; ++u) {
      const int k = k0 + u;
      // I prefetch for offset k+3 (LDS, lgkm; consumed next iter)
      Ireg[(u + 3) & 1][0] = isl[(k + 3) * 128 + ibase];
      Ireg[(u + 3) & 1][1] = isl[(k + 3) * 128 + ibase + 16];
      // stage weights k+3 (k+3 <= 26, unique) -> slot (u+3)&3
      {
        const unsigned short* src = rwT + ((size_t)(k + 3) << 12);
        unsigned short* dst = &sw[(u + 3) & 3][0];
        gload_lds16(src + s0, dst + s0);
        gload_lds16(src + s1, dst + s1);
      }
      // gather A for offset k+2 via Ireg[(u+2)&1] -> slot (u+2)&3
      CONV_GATHER((u + 2) & 3, Ireg[(u + 2) & 1][0], Ireg[(u + 2) & 1][1]);
      // counted wait: leave newest 12 (= this iter's 6 + prev iter's 6)
      asm volatile("s_waitcnt vmcnt(12)" ::: "memory");
      // compute offset k from B slot u&3, A slot u&3
      CONV_COMPUTE(u & 3, u & 3);
      __builtin_amdgcn_s_barrier();
    }
  }

  // ---- epilogue: k = 24, 25, 26 ----
  { // k=24: gather offset 26 via Ireg[26&1=0] (written at k=23) -> A slot 26&3=2
    CONV_GATHER(2, Ireg[0][0], Ireg[0][1]);
    asm volatile("s_waitcnt vmcnt(10)" ::: "memory"); // retires iter-22 ops (incl A[0])
    CONV_COMPUTE(0, 0); // k=24
    __builtin_amdgcn_s_barrier();
  }
  { // k=25: no loads
    asm volatile("s_waitcnt vmcnt(4)" ::: "memory"); // retires iter-23 (A[1], stage 26)
    CONV_COMPUTE(1, 1); // k=25
    __builtin_amdgcn_s_barrier();
  }
  { // k=26
    asm volatile("s_waitcnt vmcnt(0)" ::: "memory"); // retires gather(26)
    CONV_COMPUTE(2, 2); // k=26
  }
#undef CONV_GATHER
#undef CONV_COMPUTE

#pragma unroll
  for (int ct = 0; ct < 4; ++ct) {
    const int col = ct * 16 + m16;
    const float bias = rb[col];
#pragma unroll
    for (int rt = 0; rt < 2; ++rt)
#pragma unroll
      for (int j = 0; j < 4; ++j) {
        const int r = rowbase + rt * 16 + q * 4 + j;
        if (r < N_PTS) {
          float v = acc[rt][ct][j] + bias;
          v = v > 0.f ? v : 0.f;
          if constexpr (FUSE) v += 2.f * bf2f(res[(size_t)r * 128 + col]);
          out[(size_t)r * 64 + col] = f2bf(v);
        }
      }
  }
}

// ---- out = x + [z1 | y[:,64:]] @ w2 + b2 ; w2T staged in LDS once; 16 rows/wave ----
__global__ __launch_bounds__(256) void k_gemm_out(
    const float* __restrict__ x, const unsigned short* __restrict__ z1,
    const unsigned short* __restrict__ y, const unsigned short* __restrict__ w2T,
    const float* __restrict__ b2, float* __restrict__ out) {
  __shared__ unsigned short sw[16384]; // 32KB
  const int tid = threadIdx.x, lane = tid & 63, w = tid >> 6;
  const int m16 = lane & 15, q = lane >> 4;
#pragma unroll
  for (int r = 0; r < 8; ++r) {
    const int off = (w * 8 + r) * 512 + lane * 8;
    gload_lds16(w2T + off, &sw[off]);
  }
  __syncthreads();
  const int rowbase = blockIdx.x * 64 + w * 16;
  const int r0 = rowbase + m16;
  const int rc = r0 < N_PTS ? r0 : N_PTS - 1;
  f32x4 acc[8] = {};
#pragma unroll
  for (int kk = 0; kk < 4; ++kk) {
    const unsigned short* ap = (kk < 2)
        ? (z1 + (size_t)rc * 64 + kk * 32 + q * 8)
        : (y + (size_t)rc * 128 + 64 + (kk - 2) * 32 + q * 8);
    frag_ab a = *(const frag_ab*)ap;
#pragma unroll
    for (int ct = 0; ct < 8; ++ct) {
      const int d = ct * 16 + m16;
      const int phys = ((kk << 2) | q) ^ m16;
      frag_ab bf = *(const frag_ab*)(&sw[d * 128 + phys * 8]);
      acc[ct] = __builtin_amdgcn_mfma_f32_16x16x32_bf16(a, bf, acc[ct], 0, 0, 0);
    }
  }
#pragma unroll
  for (int ct = 0; ct < 8; ++ct) {
    const int col = ct * 16 + m16;
    const float bias = b2[col];
#pragma unroll
    for (int j = 0; j < 4; ++j) {
      int r = rowbase + q * 4 + j;
      if (r < N_PTS) {
        size_t o = (size_t)r * 128 + col;
        out[o] = acc[ct][j] + bias + x[o];
      }
    }
  }
}

extern "C" void kernel_launch(void* const* d_in, const int* in_sizes, int n_in,
                              void* d_out, int out_size, void* d_ws, size_t ws_size,
                              hipStream_t stream) {
  const float* x   = (const float*)d_in[0];
  const float* w1  = (const float*)d_in[1];
  const float* b1  = (const float*)d_in[2];
  const float* w2  = (const float*)d_in[3];
  const float* b2  = (const float*)d_in[4];
  const float* rw1 = (const float*)d_in[5];
  const float* rb1 = (const float*)d_in[6];
  const float* rw2 = (const float*)d_in[7];
  const float* rb2 = (const float*)d_in[8];
  const int* nbr = (const int*)d_in[9];
  float* out = (float*)d_out;

  char* ws = (char*)d_ws;
  unsigned short* w1T  = (unsigned short*)(ws);                       // 32 KB
  unsigned short* w2T  = (unsigned short*)(ws + 32768);               // 32 KB
  unsigned short* rw1T = (unsigned short*)(ws + 65536);               // 216 KB
  unsigned short* rw2T = (unsigned short*)(ws + 286720);              // 216 KB
  unsigned short* y    = (unsigned short*)(ws + 507904);              // 25.6 MB
  unsigned short* r1   = (unsigned short*)(ws + 507904 + 25600000);   // 12.8 MB
  unsigned short* z1   = (unsigned short*)(ws + 507904 + 38400000);   // 12.8 MB

  k_prep<<<432, 256, 0, stream>>>(w1, w2, rw1, rw2, w1T, w2T, rw1T, rw2T);
  k_gemm_in<<<NBLK64, 256, 0, stream>>>(x, w1T, b1, y);
  k_conv<false><<<NBLK128, 256, 0, stream>>>(y, 128, nbr, rw1T, rb1, nullptr, r1);
  k_conv<true><<<NBLK128, 256, 0, stream>>>(r1, 64, nbr, rw2T, rb2, y, z1);
  k_gemm_out<<<NBLK64, 256, 0, stream>>>(x, z1, y, w2T, b2, out);
}

// Round 7
// 258.022 us; speedup vs baseline: 1.5539x; 1.1256x over previous
//
#include <hip/hip_runtime.h>

// TCM_77464030151162: x(N,128)@w1+b1 -> split 64/64 -> two gathered 3^3 sparse
// convs (27 offsets, 64x64 each, ReLU) -> +2*conv_x residual -> concat@w2+b2 -> +x.
// fp32 wire, bf16 MFMA compute.
// R11: R4 (best, 47.6us/conv) + 2-offset phases. Post-mortems R5-R10: every
// protocol change (more waves, barrier-free, counted vmcnt d1/d2) lost to R4's
// plain __syncthreads dbuf; per-barrier drain exposure x27 is the cost and no
// pipe saturates. This round: amortize -- stage 2 weight slices per phase, 14
// syncs instead of 27, 2x loads in flight per drain, 32 MFMA cover per phase.
// Everything else byte-for-byte R4: guarded gathers (skip ~60% invalid nbrs),
// swizzled LDS via pre-swizzled global layout, 4 waves x 32 rows, grid 782.
// Ring discipline identical to R4 (compute reads slot p&1, writes slot (p+1)&1,
// sync separates). GEMMs/k_prep = R4 verbatim.

#define N_PTS 100000
#define NBLK128 782 // ceil(100000/128)

typedef __attribute__((ext_vector_type(8))) short frag_ab; // 8 bf16 (4 VGPRs)
typedef __attribute__((ext_vector_type(4))) float f32x4;   // MFMA 16x16 C/D
#define ZFRAG frag_ab{0, 0, 0, 0, 0, 0, 0, 0}

__device__ __forceinline__ unsigned short f2bf(float f) {
  union { float f; unsigned int i; } v; v.f = f;
  unsigned int r = v.i + 0x7fffu + ((v.i >> 16) & 1u); // RNE
  return (unsigned short)(r >> 16);
}
__device__ __forceinline__ float bf2f(unsigned short u) {
  union { unsigned int i; float f; } v; v.i = ((unsigned int)u) << 16; return v.f;
}

// async global->LDS, 16B per lane. LDS dest = wave-uniform base + lane*16 (m104).
__device__ __forceinline__ void gload_lds16(const unsigned short* g, unsigned short* l) {
  __builtin_amdgcn_global_load_lds(
      (const __attribute__((address_space(1))) unsigned int*)g,
      (__attribute__((address_space(3))) unsigned int*)(unsigned int)(size_t)l,
      16, 0, 0);
}

// ---- weight convert+transpose+swizzle ----
// w1T/w2T: logical (d,c) d=0..127 out-col, c=0..127 k. 16B chunk (c>>3) stored at
// chunk^(d&15). rw1T/rw2T: (k,d,c) 64x64; chunk (c>>3) stored at chunk^(d&7).
__global__ __launch_bounds__(256) void k_prep(
    const float* __restrict__ w1, const float* __restrict__ w2,
    const float* __restrict__ rw1, const float* __restrict__ rw2,
    unsigned short* __restrict__ w1T, unsigned short* __restrict__ w2T,
    unsigned short* __restrict__ rw1T, unsigned short* __restrict__ rw2T) {
  int t = blockIdx.x * 256 + threadIdx.x;
  if (t < 128 * 128) {
    int c = t >> 7, d = t & 127;
    int pos = d * 128 + ((((c >> 3) ^ (d & 15)) << 3) | (c & 7));
    w1T[pos] = f2bf(w1[t]);
    w2T[pos] = f2bf(w2[t]);
  }
  if (t < 27 * 64 * 64) {
    int k = t >> 12, r = t & 4095, c = r >> 6, d = r & 63;
    int pos = (k << 12) + d * 64 + ((((c >> 3) ^ (d & 7)) << 3) | (c & 7));
    rw1T[pos] = f2bf(rw1[t]);
    rw2T[pos] = f2bf(rw2[t]);
  }
}

// ---- y = bf16(x) @ w1 + b1 ; w1T staged in LDS once ---- (R4 verbatim)
__global__ __launch_bounds__(256) void k_gemm_in(
    const float* __restrict__ x, const unsigned short* __restrict__ w1T,
    const float* __restrict__ b1, unsigned short* __restrict__ y) {
  __shared__ unsigned short sw[16384]; // 32KB
  const int tid = threadIdx.x, lane = tid & 63, w = tid >> 6;
  const int m16 = lane & 15, q = lane >> 4;
#pragma unroll
  for (int r = 0; r < 8; ++r) {
    const int off = (w * 8 + r) * 512 + lane * 8;
    gload_lds16(w1T + off, &sw[off]);
  }
  __syncthreads();
  const int rowbase = blockIdx.x * 128 + w * 32;
  f32x4 acc[2][8] = {};
#pragma unroll
  for (int kk = 0; kk < 4; ++kk) {
    frag_ab a[2];
#pragma unroll
    for (int rt = 0; rt < 2; ++rt) {
      int r0 = rowbase + rt * 16 + m16;
      int rc = r0 < N_PTS ? r0 : N_PTS - 1;
      const float* xp = x + (size_t)rc * 128 + kk * 32 + q * 8;
      float4 f0 = *(const float4*)xp;
      float4 f1 = *(const float4*)(xp + 4);
      frag_ab t;
      t[0] = (short)f2bf(f0.x); t[1] = (short)f2bf(f0.y);
      t[2] = (short)f2bf(f0.z); t[3] = (short)f2bf(f0.w);
      t[4] = (short)f2bf(f1.x); t[5] = (short)f2bf(f1.y);
      t[6] = (short)f2bf(f1.z); t[7] = (short)f2bf(f1.w);
      a[rt] = t;
    }
#pragma unroll
    for (int ct = 0; ct < 8; ++ct) {
      const int d = ct * 16 + m16;
      const int phys = ((kk << 2) | q) ^ m16;
      frag_ab bf = *(const frag_ab*)(&sw[d * 128 + phys * 8]);
      acc[0][ct] = __builtin_amdgcn_mfma_f32_16x16x32_bf16(a[0], bf, acc[0][ct], 0, 0, 0);
      acc[1][ct] = __builtin_amdgcn_mfma_f32_16x16x32_bf16(a[1], bf, acc[1][ct], 0, 0, 0);
    }
  }
#pragma unroll
  for (int ct = 0; ct < 8; ++ct) {
    const int col = ct * 16 + m16;
    const float bias = b1[col];
#pragma unroll
    for (int rt = 0; rt < 2; ++rt)
#pragma unroll
      for (int j = 0; j < 4; ++j) {
        int r = rowbase + rt * 16 + q * 4 + j;
        if (r < N_PTS) y[(size_t)r * 128 + col] = f2bf(acc[rt][ct][j] + bias);
      }
  }
}

// ---- gathered sparse conv: R4 structure, 2 offsets per phase ----
// 14 phases over 27 offsets. Per phase p: stage offsets 2p+2,2p+3 into buf
// (p+1)&1; idx prefetch for phase p+2; gather A for phase p+1 (guarded,
// exec-masked skip of invalid neighbors); compute offsets 2p,2p+1 (32 MFMA);
// __syncthreads. All ring indices compile-time (outer loop unroll-2).
template <bool FUSE>
__global__ __launch_bounds__(256) void k_conv(
    const unsigned short* __restrict__ feat, const int fstride,
    const int* __restrict__ nbr,
    const unsigned short* __restrict__ rwT, const float* __restrict__ rb,
    const unsigned short* __restrict__ res, unsigned short* __restrict__ out) {
  __shared__ unsigned short sw[2][2][4096]; // [phase-ring][offset][slice] 32KB
  const int tid = threadIdx.x, lane = tid & 63, w = tid >> 6;
  const int m16 = lane & 15, q = lane >> 4;
  const int rowbase = blockIdx.x * 128 + w * 32;
  const int p0 = rowbase + m16, p1 = p0 + 16;
  const bool v0 = p0 < N_PTS, v1 = p1 < N_PTS;
  const int s0 = w * 1024 + lane * 8; // ushort index of this thread's 16B chunk
  const int s1 = s0 + 512;

  int I[2][2][2];        // [phase-parity][offset][rowpair]
  frag_ab A[2][2][2][2]; // [phase-parity][offset][rt][kk]
  f32x4 acc[2][4] = {};

#define STAGE(buf, o, koff)                                                     \
  {                                                                             \
    const unsigned short* src = rwT + ((size_t)(koff) << 12);                   \
    unsigned short* dst = &sw[buf][o][0];                                       \
    gload_lds16(src + s0, dst + s0);                                            \
    gload_lds16(src + s1, dst + s1);                                            \
  }

#define IDXLOAD(pp, o, koff)                                                    \
  {                                                                             \
    I[pp][o][0] = v0 ? nbr[(size_t)(koff) * N_PTS + p0] : -1;                   \
    I[pp][o][1] = v1 ? nbr[(size_t)(koff) * N_PTS + p1] : -1;                   \
  }

#define GATHER(pp, o)                                                           \
  {                                                                             \
    A[pp][o][0][0] = ZFRAG; A[pp][o][0][1] = ZFRAG;                             \
    A[pp][o][1][0] = ZFRAG; A[pp][o][1][1] = ZFRAG;                             \
    const int j0 = I[pp][o][0], j1 = I[pp][o][1];                               \
    if (j0 >= 0) {                                                              \
      const unsigned short* fp = feat + (size_t)j0 * fstride + q * 8;           \
      A[pp][o][0][0] = *(const frag_ab*)fp;                                     \
      A[pp][o][0][1] = *(const frag_ab*)(fp + 32);                              \
    }                                                                           \
    if (j1 >= 0) {                                                              \
      const unsigned short* fp = feat + (size_t)j1 * fstride + q * 8;           \
      A[pp][o][1][0] = *(const frag_ab*)fp;                                     \
      A[pp][o][1][1] = *(const frag_ab*)(fp + 32);                              \
    }                                                                           \
  }

#define COMPUTE(cur, o)                                                         \
  _Pragma("unroll") for (int kk = 0; kk < 2; ++kk)                              \
    _Pragma("unroll") for (int ct = 0; ct < 4; ++ct) {                          \
      const int d = ct * 16 + m16;                                              \
      const int phys = ((kk << 2) | q) ^ (m16 & 7);                             \
      frag_ab bf = *(const frag_ab*)(&sw[cur][o][d * 64 + phys * 8]);           \
      acc[0][ct] = __builtin_amdgcn_mfma_f32_16x16x32_bf16(A[cur][o][0][kk], bf, acc[0][ct], 0, 0, 0); \
      acc[1][ct] = __builtin_amdgcn_mfma_f32_16x16x32_bf16(A[cur][o][1][kk], bf, acc[1][ct], 0, 0, 0); \
    }

  // ---- prologue: idx for phases 0,1; stage phase 0; gather phase 0 ----
  IDXLOAD(0, 0, 0); IDXLOAD(0, 1, 1);
  IDXLOAD(1, 0, 2); IDXLOAD(1, 1, 3);
  STAGE(0, 0, 0); STAGE(0, 1, 1);
  GATHER(0, 0); GATHER(0, 1);
  __syncthreads();

  // ---- main phases p = 0..11 (outer runtime, inner unroll-2: static indices) ----
  for (int pout = 0; pout < 6; ++pout) {
#pragma unroll
    for (int u = 0; u < 2; ++u) {
      const int p = pout * 2 + u;
      const int nxt = u ^ 1;
      // stage weights for phase p+1 (offsets 2p+2, 2p+3; <= 25)
      STAGE(nxt, 0, 2 * p + 2);
      STAGE(nxt, 1, 2 * p + 3);
      // idx prefetch for phase p+2 -> slot (p+2)&1 == u
      if (p < 11) {
        IDXLOAD(u, 0, 2 * p + 4);
        IDXLOAD(u, 1, 2 * p + 5);
      } else { // p == 11: phase 13 has only offset 26
        IDXLOAD(u, 0, 26);
      }
      // gather A for phase p+1 (idx loaded at p-1, drained by sync end of p-1)
      GATHER(nxt, 0);
      GATHER(nxt, 1);
      // compute offsets 2p, 2p+1
      COMPUTE(u, 0);
      COMPUTE(u, 1);
      __syncthreads();
    }
  }

  // ---- phase 12 (parity 0): stage offset 26, gather it, compute 24,25 ----
  STAGE(1, 0, 26);
  GATHER(1, 0); // offset 26 via I[1][0] (loaded at p=11)
  COMPUTE(0, 0);
  COMPUTE(0, 1);
  __syncthreads();
  // ---- phase 13 (parity 1): compute offset 26 ----
  COMPUTE(1, 0);

#undef STAGE
#undef IDXLOAD
#undef GATHER
#undef COMPUTE

#pragma unroll
  for (int ct = 0; ct < 4; ++ct) {
    const int col = ct * 16 + m16;
    const float bias = rb[col];
#pragma unroll
    for (int rt = 0; rt < 2; ++rt)
#pragma unroll
      for (int j = 0; j < 4; ++j) {
        const int r = rowbase + rt * 16 + q * 4 + j;
        if (r < N_PTS) {
          float v = acc[rt][ct][j] + bias;
          v = v > 0.f ? v : 0.f;
          if constexpr (FUSE) v += 2.f * bf2f(res[(size_t)r * 128 + col]);
          out[(size_t)r * 64 + col] = f2bf(v);
        }
      }
  }
}

// ---- out = x + [z1 | y[:,64:]] @ w2 + b2 ; w2T staged in LDS once ---- (R4 verbatim)
__global__ __launch_bounds__(256) void k_gemm_out(
    const float* __restrict__ x, const unsigned short* __restrict__ z1,
    const unsigned short* __restrict__ y, const unsigned short* __restrict__ w2T,
    const float* __restrict__ b2, float* __restrict__ out) {
  __shared__ unsigned short sw[16384]; // 32KB
  const int tid = threadIdx.x, lane = tid & 63, w = tid >> 6;
  const int m16 = lane & 15, q = lane >> 4;
#pragma unroll
  for (int r = 0; r < 8; ++r) {
    const int off = (w * 8 + r) * 512 + lane * 8;
    gload_lds16(w2T + off, &sw[off]);
  }
  __syncthreads();
  const int rowbase = blockIdx.x * 128 + w * 32;
  f32x4 acc[2][8] = {};
#pragma unroll
  for (int kk = 0; kk < 4; ++kk) {
    frag_ab a[2];
#pragma unroll
    for (int rt = 0; rt < 2; ++rt) {
      int r0 = rowbase + rt * 16 + m16;
      int rc = r0 < N_PTS ? r0 : N_PTS - 1;
      const unsigned short* ap = (kk < 2)
          ? (z1 + (size_t)rc * 64 + kk * 32 + q * 8)
          : (y + (size_t)rc * 128 + 64 + (kk - 2) * 32 + q * 8);
      a[rt] = *(const frag_ab*)ap;
    }
#pragma unroll
    for (int ct = 0; ct < 8; ++ct) {
      const int d = ct * 16 + m16;
      const int phys = ((kk << 2) | q) ^ m16;
      frag_ab bf = *(const frag_ab*)(&sw[d * 128 + phys * 8]);
      acc[0][ct] = __builtin_amdgcn_mfma_f32_16x16x32_bf16(a[0], bf, acc[0][ct], 0, 0, 0);
      acc[1][ct] = __builtin_amdgcn_mfma_f32_16x16x32_bf16(a[1], bf, acc[1][ct], 0, 0, 0);
    }
  }
#pragma unroll
  for (int ct = 0; ct < 8; ++ct) {
    const int col = ct * 16 + m16;
    const float bias = b2[col];
#pragma unroll
    for (int rt = 0; rt < 2; ++rt)
#pragma unroll
      for (int j = 0; j < 4; ++j) {
        int r = rowbase + rt * 16 + q * 4 + j;
        if (r < N_PTS) {
          size_t o = (size_t)r * 128 + col;
          out[o] = acc[rt][ct][j] + bias + x[o];
        }
      }
  }
}

extern "C" void kernel_launch(void* const* d_in, const int* in_sizes, int n_in,
                              void* d_out, int out_size, void* d_ws, size_t ws_size,
                              hipStream_t stream) {
  const float* x   = (const float*)d_in[0];
  const float* w1  = (const float*)d_in[1];
  const float* b1  = (const float*)d_in[2];
  const float* w2  = (const float*)d_in[3];
  const float* b2  = (const float*)d_in[4];
  const float* rw1 = (const float*)d_in[5];
  const float* rb1 = (const float*)d_in[6];
  const float* rw2 = (const float*)d_in[7];
  const float* rb2 = (const float*)d_in[8];
  const int* nbr = (const int*)d_in[9];
  float* out = (float*)d_out;

  char* ws = (char*)d_ws;
  unsigned short* w1T  = (unsigned short*)(ws);                       // 32 KB
  unsigned short* w2T  = (unsigned short*)(ws + 32768);               // 32 KB
  unsigned short* rw1T = (unsigned short*)(ws + 65536);               // 216 KB
  unsigned short* rw2T = (unsigned short*)(ws + 286720);              // 216 KB
  unsigned short* y    = (unsigned short*)(ws + 507904);              // 25.6 MB
  unsigned short* r1   = (unsigned short*)(ws + 507904 + 25600000);   // 12.8 MB
  unsigned short* z1   = (unsigned short*)(ws + 507904 + 38400000);   // 12.8 MB

  k_prep<<<432, 256, 0, stream>>>(w1, w2, rw1, rw2, w1T, w2T, rw1T, rw2T);
  k_gemm_in<<<NBLK128, 256, 0, stream>>>(x, w1T, b1, y);
  k_conv<false><<<NBLK128, 256, 0, stream>>>(y, 128, nbr, rw1T, rb1, nullptr, r1);
  k_conv<true><<<NBLK128, 256, 0, stream>>>(r1, 64, nbr, rw2T, rb2, y, z1);
  k_gemm_out<<<NBLK128, 256, 0, stream>>>(x, z1, y, w2T, b2, out);
}

// Round 8
// 250.031 us; speedup vs baseline: 1.6036x; 1.0320x over previous
//
#include <hip/hip_runtime.h>

// TCM_77464030151162: x(N,128)@w1+b1 -> split 64/64 -> two gathered 3^3 sparse
// convs (27 offsets, 64x64 each, ReLU) -> +2*conv_x residual -> concat@w2+b2 -> +x.
// fp32 wire, bf16 MFMA compute.
// R12: conv = R4 per-wave-identical, regrouped into 64-row blocks of TWO 32-row
// waves (128 thr). Grid 782->1563 (6.1 blocks/CU: finer residency granularity),
// barrier domain 4->2 waves (drain waits on half the straggler gathers), LDS
// 16KB. Per-wave LDS reads / gathers / MFMA unchanged (R5's trap was 16-row
// waves doubling LDS-read work -- avoided). Stage traffic 2x (L2, ~+3us spread).
// Gathers issued before stage in each phase (longest-latency first).
// Six failed conv variants (R5 waves++, R6/R9 barrier-free, R7/R8/R10 counted
// vmcnt, R11 2-offset phases) say: keep R4's exact phase discipline.
// GEMMs/k_prep = R0/R4 verbatim.

#define N_PTS 100000
#define NBLK128 782  // ceil(100000/128)
#define NBLK64 1563  // ceil(100000/64)

typedef __attribute__((ext_vector_type(8))) short frag_ab; // 8 bf16 (4 VGPRs)
typedef __attribute__((ext_vector_type(4))) float f32x4;   // MFMA 16x16 C/D
#define ZFRAG frag_ab{0, 0, 0, 0, 0, 0, 0, 0}

__device__ __forceinline__ unsigned short f2bf(float f) {
  union { float f; unsigned int i; } v; v.f = f;
  unsigned int r = v.i + 0x7fffu + ((v.i >> 16) & 1u); // RNE
  return (unsigned short)(r >> 16);
}
__device__ __forceinline__ float bf2f(unsigned short u) {
  union { unsigned int i; float f; } v; v.i = ((unsigned int)u) << 16; return v.f;
}

// async global->LDS, 16B per lane. LDS dest = wave-uniform base + lane*16 (m104).
__device__ __forceinline__ void gload_lds16(const unsigned short* g, unsigned short* l) {
  __builtin_amdgcn_global_load_lds(
      (const __attribute__((address_space(1))) unsigned int*)g,
      (__attribute__((address_space(3))) unsigned int*)(unsigned int)(size_t)l,
      16, 0, 0);
}

// ---- weight convert+transpose+swizzle ----
// w1T/w2T: logical (d,c) d=0..127 out-col, c=0..127 k. 16B chunk (c>>3) stored at
// chunk^(d&15). rw1T/rw2T: (k,d,c) 64x64; chunk (c>>3) stored at chunk^(d&7).
__global__ __launch_bounds__(256) void k_prep(
    const float* __restrict__ w1, const float* __restrict__ w2,
    const float* __restrict__ rw1, const float* __restrict__ rw2,
    unsigned short* __restrict__ w1T, unsigned short* __restrict__ w2T,
    unsigned short* __restrict__ rw1T, unsigned short* __restrict__ rw2T) {
  int t = blockIdx.x * 256 + threadIdx.x;
  if (t < 128 * 128) {
    int c = t >> 7, d = t & 127;
    int pos = d * 128 + ((((c >> 3) ^ (d & 15)) << 3) | (c & 7));
    w1T[pos] = f2bf(w1[t]);
    w2T[pos] = f2bf(w2[t]);
  }
  if (t < 27 * 64 * 64) {
    int k = t >> 12, r = t & 4095, c = r >> 6, d = r & 63;
    int pos = (k << 12) + d * 64 + ((((c >> 3) ^ (d & 7)) << 3) | (c & 7));
    rw1T[pos] = f2bf(rw1[t]);
    rw2T[pos] = f2bf(rw2[t]);
  }
}

// ---- y = bf16(x) @ w1 + b1 ; w1T staged in LDS once ---- (R4 verbatim)
__global__ __launch_bounds__(256) void k_gemm_in(
    const float* __restrict__ x, const unsigned short* __restrict__ w1T,
    const float* __restrict__ b1, unsigned short* __restrict__ y) {
  __shared__ unsigned short sw[16384]; // 32KB
  const int tid = threadIdx.x, lane = tid & 63, w = tid >> 6;
  const int m16 = lane & 15, q = lane >> 4;
#pragma unroll
  for (int r = 0; r < 8; ++r) {
    const int off = (w * 8 + r) * 512 + lane * 8;
    gload_lds16(w1T + off, &sw[off]);
  }
  __syncthreads();
  const int rowbase = blockIdx.x * 128 + w * 32;
  f32x4 acc[2][8] = {};
#pragma unroll
  for (int kk = 0; kk < 4; ++kk) {
    frag_ab a[2];
#pragma unroll
    for (int rt = 0; rt < 2; ++rt) {
      int r0 = rowbase + rt * 16 + m16;
      int rc = r0 < N_PTS ? r0 : N_PTS - 1;
      const float* xp = x + (size_t)rc * 128 + kk * 32 + q * 8;
      float4 f0 = *(const float4*)xp;
      float4 f1 = *(const float4*)(xp + 4);
      frag_ab t;
      t[0] = (short)f2bf(f0.x); t[1] = (short)f2bf(f0.y);
      t[2] = (short)f2bf(f0.z); t[3] = (short)f2bf(f0.w);
      t[4] = (short)f2bf(f1.x); t[5] = (short)f2bf(f1.y);
      t[6] = (short)f2bf(f1.z); t[7] = (short)f2bf(f1.w);
      a[rt] = t;
    }
#pragma unroll
    for (int ct = 0; ct < 8; ++ct) {
      const int d = ct * 16 + m16;
      const int phys = ((kk << 2) | q) ^ m16;
      frag_ab bf = *(const frag_ab*)(&sw[d * 128 + phys * 8]);
      acc[0][ct] = __builtin_amdgcn_mfma_f32_16x16x32_bf16(a[0], bf, acc[0][ct], 0, 0, 0);
      acc[1][ct] = __builtin_amdgcn_mfma_f32_16x16x32_bf16(a[1], bf, acc[1][ct], 0, 0, 0);
    }
  }
#pragma unroll
  for (int ct = 0; ct < 8; ++ct) {
    const int col = ct * 16 + m16;
    const float bias = b1[col];
#pragma unroll
    for (int rt = 0; rt < 2; ++rt)
#pragma unroll
      for (int j = 0; j < 4; ++j) {
        int r = rowbase + rt * 16 + q * 4 + j;
        if (r < N_PTS) y[(size_t)r * 128 + col] = f2bf(acc[rt][ct][j] + bias);
      }
  }
}

// ---- gathered sparse conv: R4 phase discipline, 2-wave blocks ----
// 64 rows/block = 2 waves x 32 rows. Per wave identical to R4: dbuf LDS B
// (ping-pong 8KB slices), idx prefetch dist 2, A-gather + stage dist 1,
// __syncthreads per offset. Staging: 4 x gload_lds per thread per offset
// (128 threads x 4 x 16B = 8KB).
template <bool FUSE>
__global__ __launch_bounds__(128) void k_conv(
    const unsigned short* __restrict__ feat, const int fstride,
    const int* __restrict__ nbr,
    const unsigned short* __restrict__ rwT, const float* __restrict__ rb,
    const unsigned short* __restrict__ res, unsigned short* __restrict__ out) {
  __shared__ unsigned short sw[2][4096]; // 2 x 8KB ping-pong
  const int tid = threadIdx.x, lane = tid & 63, w = tid >> 6; // w in {0,1}
  const int m16 = lane & 15, q = lane >> 4;
  const int rowbase = blockIdx.x * 64 + w * 32;
  const int p0 = rowbase + m16, p1 = p0 + 16;
  const bool v0 = p0 < N_PTS, v1 = p1 < N_PTS;
  const int sbase = w * 2048 + lane * 8; // ushort idx; 4 chunks: +r*512, r=0..3

  int i0r[2], i1r[2];
  i0r[0] = v0 ? nbr[p0] : -1;
  i1r[0] = v1 ? nbr[p1] : -1;
  i0r[1] = v0 ? nbr[N_PTS + p0] : -1;
  i1r[1] = v1 ? nbr[N_PTS + p1] : -1;

  frag_ab A[2][2][2]; // [ring][rt][kk]
#pragma unroll
  for (int a = 0; a < 2; ++a)
#pragma unroll
    for (int b = 0; b < 2; ++b)
#pragma unroll
      for (int c = 0; c < 2; ++c) A[a][b][c] = ZFRAG;

  { // gather A for k=0, stage k=0
    if (i0r[0] >= 0) {
      const unsigned short* fp = feat + (size_t)i0r[0] * fstride + q * 8;
      A[0][0][0] = *(const frag_ab*)fp; A[0][0][1] = *(const frag_ab*)(fp + 32);
    }
    if (i1r[0] >= 0) {
      const unsigned short* fp = feat + (size_t)i1r[0] * fstride + q * 8;
      A[0][1][0] = *(const frag_ab*)fp; A[0][1][1] = *(const frag_ab*)(fp + 32);
    }
#pragma unroll
    for (int r = 0; r < 4; ++r)
      gload_lds16(rwT + sbase + r * 512, &sw[0][sbase + r * 512]);
  }
  __syncthreads();

  f32x4 acc[2][4] = {};
#pragma unroll
  for (int k = 0; k < 27; ++k) {
    const int b = k & 1;
    if (k + 1 < 27) {
      // gather A for k+1 (indices already resolved) -- longest latency first
      const int n = (k + 1) & 1;
      int j0 = i0r[n], j1 = i1r[n];
      A[n][0][0] = ZFRAG; A[n][0][1] = ZFRAG; A[n][1][0] = ZFRAG; A[n][1][1] = ZFRAG;
      if (j0 >= 0) {
        const unsigned short* fp = feat + (size_t)j0 * fstride + q * 8;
        A[n][0][0] = *(const frag_ab*)fp; A[n][0][1] = *(const frag_ab*)(fp + 32);
      }
      if (j1 >= 0) {
        const unsigned short* fp = feat + (size_t)j1 * fstride + q * 8;
        A[n][1][0] = *(const frag_ab*)fp; A[n][1][1] = *(const frag_ab*)(fp + 32);
      }
      // stage weights for k+1 into other buffer
      const unsigned short* src = rwT + ((size_t)(k + 1) << 12);
#pragma unroll
      for (int r = 0; r < 4; ++r)
        gload_lds16(src + sbase + r * 512, &sw[b ^ 1][sbase + r * 512]);
    }
    if (k + 2 < 27) {
      i0r[k & 1] = v0 ? nbr[(size_t)(k + 2) * N_PTS + p0] : -1;
      i1r[k & 1] = v1 ? nbr[(size_t)(k + 2) * N_PTS + p1] : -1;
    }
    // compute k from sw[b], A[b]
#pragma unroll
    for (int kk = 0; kk < 2; ++kk)
#pragma unroll
      for (int ct = 0; ct < 4; ++ct) {
        const int d = ct * 16 + m16;
        const int phys = ((kk << 2) | q) ^ (m16 & 7);
        frag_ab bf = *(const frag_ab*)(&sw[b][d * 64 + phys * 8]);
        acc[0][ct] = __builtin_amdgcn_mfma_f32_16x16x32_bf16(A[b][0][kk], bf, acc[0][ct], 0, 0, 0);
        acc[1][ct] = __builtin_amdgcn_mfma_f32_16x16x32_bf16(A[b][1][kk], bf, acc[1][ct], 0, 0, 0);
      }
    __syncthreads();
  }

#pragma unroll
  for (int ct = 0; ct < 4; ++ct) {
    const int col = ct * 16 + m16;
    const float bias = rb[col];
#pragma unroll
    for (int rt = 0; rt < 2; ++rt)
#pragma unroll
      for (int j = 0; j < 4; ++j) {
        const int r = rowbase + rt * 16 + q * 4 + j;
        if (r < N_PTS) {
          float v = acc[rt][ct][j] + bias;
          v = v > 0.f ? v : 0.f;
          if constexpr (FUSE) v += 2.f * bf2f(res[(size_t)r * 128 + col]);
          out[(size_t)r * 64 + col] = f2bf(v);
        }
      }
  }
}

// ---- out = x + [z1 | y[:,64:]] @ w2 + b2 ; w2T staged in LDS once ---- (R4 verbatim)
__global__ __launch_bounds__(256) void k_gemm_out(
    const float* __restrict__ x, const unsigned short* __restrict__ z1,
    const unsigned short* __restrict__ y, const unsigned short* __restrict__ w2T,
    const float* __restrict__ b2, float* __restrict__ out) {
  __shared__ unsigned short sw[16384]; // 32KB
  const int tid = threadIdx.x, lane = tid & 63, w = tid >> 6;
  const int m16 = lane & 15, q = lane >> 4;
#pragma unroll
  for (int r = 0; r < 8; ++r) {
    const int off = (w * 8 + r) * 512 + lane * 8;
    gload_lds16(w2T + off, &sw[off]);
  }
  __syncthreads();
  const int rowbase = blockIdx.x * 128 + w * 32;
  f32x4 acc[2][8] = {};
#pragma unroll
  for (int kk = 0; kk < 4; ++kk) {
    frag_ab a[2];
#pragma unroll
    for (int rt = 0; rt < 2; ++rt) {
      int r0 = rowbase + rt * 16 + m16;
      int rc = r0 < N_PTS ? r0 : N_PTS - 1;
      const unsigned short* ap = (kk < 2)
          ? (z1 + (size_t)rc * 64 + kk * 32 + q * 8)
          : (y + (size_t)rc * 128 + 64 + (kk - 2) * 32 + q * 8);
      a[rt] = *(const frag_ab*)ap;
    }
#pragma unroll
    for (int ct = 0; ct < 8; ++ct) {
      const int d = ct * 16 + m16;
      const int phys = ((kk << 2) | q) ^ m16;
      frag_ab bf = *(const frag_ab*)(&sw[d * 128 + phys * 8]);
      acc[0][ct] = __builtin_amdgcn_mfma_f32_16x16x32_bf16(a[0], bf, acc[0][ct], 0, 0, 0);
      acc[1][ct] = __builtin_amdgcn_mfma_f32_16x16x32_bf16(a[1], bf, acc[1][ct], 0, 0, 0);
    }
  }
#pragma unroll
  for (int ct = 0; ct < 8; ++ct) {
    const int col = ct * 16 + m16;
    const float bias = b2[col];
#pragma unroll
    for (int rt = 0; rt < 2; ++rt)
#pragma unroll
      for (int j = 0; j < 4; ++j) {
        int r = rowbase + rt * 16 + q * 4 + j;
        if (r < N_PTS) {
          size_t o = (size_t)r * 128 + col;
          out[o] = acc[rt][ct][j] + bias + x[o];
        }
      }
  }
}

extern "C" void kernel_launch(void* const* d_in, const int* in_sizes, int n_in,
                              void* d_out, int out_size, void* d_ws, size_t ws_size,
                              hipStream_t stream) {
  const float* x   = (const float*)d_in[0];
  const float* w1  = (const float*)d_in[1];
  const float* b1  = (const float*)d_in[2];
  const float* w2  = (const float*)d_in[3];
  const float* b2  = (const float*)d_in[4];
  const float* rw1 = (const float*)d_in[5];
  const float* rb1 = (const float*)d_in[6];
  const float* rw2 = (const float*)d_in[7];
  const float* rb2 = (const float*)d_in[8];
  const int* nbr = (const int*)d_in[9];
  float* out = (float*)d_out;

  char* ws = (char*)d_ws;
  unsigned short* w1T  = (unsigned short*)(ws);                       // 32 KB
  unsigned short* w2T  = (unsigned short*)(ws + 32768);               // 32 KB
  unsigned short* rw1T = (unsigned short*)(ws + 65536);               // 216 KB
  unsigned short* rw2T = (unsigned short*)(ws + 286720);              // 216 KB
  unsigned short* y    = (unsigned short*)(ws + 507904);              // 25.6 MB
  unsigned short* r1   = (unsigned short*)(ws + 507904 + 25600000);   // 12.8 MB
  unsigned short* z1   = (unsigned short*)(ws + 507904 + 38400000);   // 12.8 MB

  k_prep<<<432, 256, 0, stream>>>(w1, w2, rw1, rw2, w1T, w2T, rw1T, rw2T);
  k_gemm_in<<<NBLK128, 256, 0, stream>>>(x, w1T, b1, y);
  k_conv<false><<<NBLK64, 128, 0, stream>>>(y, 128, nbr, rw1T, rb1, nullptr, r1);
  k_conv<true><<<NBLK64, 128, 0, stream>>>(r1, 64, nbr, rw2T, rb2, y, z1);
  k_gemm_out<<<NBLK128, 256, 0, stream>>>(x, z1, y, w2T, b2, out);
}